// Round 10
// baseline (388.838 us; speedup 1.0000x reference)
//
#include <hip/hip_runtime.h>
#include <hip/hip_bf16.h>

// GCN: x=emb[ids]; x1=relu(GCNConv(x,W1,b1)); y=Ahat@x1; out[g]=b2+(mean_g y)@W2
//
// Structure (R10):
//  - conv1: rank-17 input -> t1=(emb@W1); per-node 17 type bins (edge atomics)
//    then dense 17-term FMA -> x1 (bf16x2, lane holds feats {lane, lane+64}).
//  - conv2+pool edge-parallel: items (E edges + N self loops) partitioned BY
//    GRAPH (two-pass deterministic), per-graph register accumulation.
//  - R10 (post-mortem of R9: partbin invariant to occupancy -> L2 atomic
//    SAME-LINE serialization is the binder):
//    * C replicated x2 by item parity (halves per-line RMW multiplicity)
//    * deg folded into C row slot 17 as fp32 (was 16 counters/line = ~256
//      serialized RMWs per line; now spread over 80B rows x 2 replicas)
//    * batch[dst] random gather replaced by 6-step LDS bsearch over gBound
//      (batch is sorted); g8 buffer deleted
//    * conv2g 16-wide gather unroll (was 8)

#define DDIM 128
#define CPAD 20      // C row stride: slots 0..16 = type bins, 17 = deg, 18-19 pad
#define GMAX 64
#define NPB  2048    // partition blocks (fixed item ranges)
#define SLICES 32    // conv2 blocks per graph
typedef unsigned int uint;

__device__ __forceinline__ float bflo(uint v) { return __uint_as_float(v << 16); }
__device__ __forceinline__ float bfhi(uint v) { return __uint_as_float(v & 0xffff0000u); }
__device__ __forceinline__ uint packbf(float x, float y) {  // RNE round both
    uint ux = __float_as_uint(x), uy = __float_as_uint(y);
    ux = (ux + 0x7fff + ((ux >> 16) & 1)) >> 16;
    uy = (uy + 0x7fff + ((uy >> 16) & 1)) & 0xffff0000u;
    return ux | uy;
}

// gBound[g] = first node index with batch >= g (batch sorted). 65 entries.
__global__ void k_gb(const int* __restrict__ batch, int* __restrict__ gBound, int N) {
    int g = threadIdx.x;
    if (g > GMAX) return;
    int lo = 0, hi = N;
    while (lo < hi) {
        int mid = (lo + hi) >> 1;
        if (batch[mid] < g) lo = mid + 1; else hi = mid;
    }
    gBound[g] = lo;
}

// Pass 1: deg (fp32, into Crep slot 17, replica by item parity) + per-block
// per-graph histogram. Graph id via LDS bsearch (no random batch gather).
__global__ void __launch_bounds__(256) k_p1(
        const int* __restrict__ dst, const int* __restrict__ gBound,
        float* __restrict__ Crep, int* __restrict__ blockHist, int E, int M, int N) {
    __shared__ int h[4][GMAX];
    __shared__ int gb[GMAX + 1];
    int t = threadIdx.x, wave = t >> 6;
    if ((t & 63) < GMAX) h[wave][t & 63] = 0;
    if (t <= GMAX) gb[t] = gBound[t];
    __syncthreads();
    int per = (M + NPB - 1) / NPB;
    int lo = blockIdx.x * per;
    int hi = lo + per; if (hi > M) hi = M;
    for (int cb = lo; cb < hi; cb += 1024) {
        int idx_[4]; bool v_[4], isE_[4];
#pragma unroll
        for (int q = 0; q < 4; q++) {
            int item = cb + q * 256 + t;
            v_[q] = item < hi;
            isE_[q] = item < E;
            idx_[q] = 0;
            if (v_[q]) idx_[q] = isE_[q] ? dst[item] : (item - E);
        }
#pragma unroll
        for (int q = 0; q < 4; q++) {
            if (v_[q]) {
                int idx = idx_[q];
                int glo = 0, ghi = GMAX - 1;
#pragma unroll
                for (int it2 = 0; it2 < 6; it2++) {
                    int mid = (glo + ghi + 1) >> 1;
                    if (gb[mid] <= idx) glo = mid; else ghi = mid - 1;
                }
                if (isE_[q]) {
                    int item = cb + q * 256 + t;
                    atomicAdd(&Crep[((size_t)(item & 1) * N + idx) * CPAD + 17], 1.0f);
                }
                atomicAdd(&h[wave][glo], 1);
            }
        }
    }
    __syncthreads();
    if (t < GMAX)
        blockHist[blockIdx.x * GMAX + t] = h[0][t] + h[1][t] + h[2][t] + h[3][t];
}

// Per-graph parallel exclusive scan over NPB block histograms.
__global__ void __launch_bounds__(256) k_scanG(
        const int* __restrict__ blockHist, int* __restrict__ localBase,
        int* __restrict__ tot) {
    __shared__ int sm[256];
    int g = blockIdx.x, t = threadIdx.x;
    const int PER = NPB / 256;     // 8
    int v[PER], loc[PER];
    int run = 0;
#pragma unroll
    for (int q = 0; q < PER; q++) {
        v[q] = blockHist[(t * PER + q) * GMAX + g];
        loc[q] = run;
        run += v[q];
    }
    sm[t] = run; __syncthreads();
    for (int off = 1; off < 256; off <<= 1) {
        int a = (t >= off) ? sm[t - off] : 0;
        __syncthreads();
        sm[t] += a; __syncthreads();
    }
    int excl = sm[t] - run;
#pragma unroll
    for (int q = 0; q < PER; q++)
        localBase[(t * PER + q) * GMAX + g] = excl + loc[q];
    if (t == 255) tot[g] = sm[255];
}

__global__ void k_scanT(const int* __restrict__ tot, int* __restrict__ gStart) {
    if (threadIdx.x == 0) {
        int run = 0;
        for (int g = 0; g < GMAX; g++) { gStart[g] = run; run += tot[g]; }
        gStart[GMAX] = run;
    }
}

// nd[i] = {dinv_i, type_i bits}; deg read from Crep slot 17 (both replicas)
__global__ void k_pack(const float* __restrict__ Crep, const int* __restrict__ ids,
                       float2* __restrict__ nd, int N) {
    int i = blockIdx.x * blockDim.x + threadIdx.x;
    if (i < N) {
        float degf = Crep[(size_t)i * CPAD + 17] + Crep[((size_t)N + i) * CPAD + 17];
        float dinv = rsqrtf(degf + 1.0f);
        nd[i] = make_float2(dinv, __int_as_float(ids[i]));
    }
}

// Pass 2 (fused): partition items into parts[]={src bits, w} by graph
// AND accumulate conv1 type bins Crep[item&1][d][type_s] += dinv_s.
__global__ void __launch_bounds__(256) k_partbin(
        const int* __restrict__ src, const int* __restrict__ dst,
        const int* __restrict__ gBound, const float2* __restrict__ nd,
        const int* __restrict__ localBase, const int* __restrict__ gStart,
        float2* __restrict__ parts, float* __restrict__ Crep, int E, int M, int N) {
    __shared__ int rk[GMAX];
    __shared__ int base[GMAX];
    __shared__ int gb[GMAX + 1];
    int t = threadIdx.x, b = blockIdx.x;
    if (t < GMAX) base[t] = gStart[t] + localBase[b * GMAX + t];
    if (t <= GMAX) gb[t] = gBound[t];
    int per = (M + NPB - 1) / NPB;
    int lo = b * per;
    int hi = lo + per; if (hi > M) hi = M;
    for (int cb = lo; cb < hi; cb += 1024) {
        if (t < GMAX) rk[t] = 0;
        __syncthreads();
        int s_[4], g_[4], r_[4], d_[4]; float w_[4]; bool v_[4], isE_[4];
#pragma unroll
        for (int q = 0; q < 4; q++) {            // batched independent loads
            int item = cb + q * 256 + t;
            v_[q] = item < hi;
            isE_[q] = item < E;
            s_[q] = 0; d_[q] = 0; g_[q] = 0; r_[q] = 0; w_[q] = 0.f;
            if (v_[q]) {
                if (isE_[q]) { s_[q] = src[item]; d_[q] = dst[item]; }
                else         { s_[q] = item - E;  d_[q] = item - E; }
            }
        }
#pragma unroll
        for (int q = 0; q < 4; q++) {            // gathers batched in flight
            if (v_[q]) {
                int idx = d_[q];
                int glo = 0, ghi = GMAX - 1;
#pragma unroll
                for (int it2 = 0; it2 < 6; it2++) {
                    int mid = (glo + ghi + 1) >> 1;
                    if (gb[mid] <= idx) glo = mid; else ghi = mid - 1;
                }
                g_[q] = glo;
                float2 ns = nd[s_[q]];
                float dd = nd[d_[q]].x;
                w_[q] = ns.x * dd;
                if (isE_[q]) {                   // conv1 bin (fire-and-forget)
                    int item = cb + q * 256 + t;
                    atomicAdd(&Crep[((size_t)(item & 1) * N + d_[q]) * CPAD
                                    + __float_as_int(ns.y)], ns.x);
                }
                r_[q] = atomicAdd(&rk[g_[q]], 1);
            }
        }
        __syncthreads();
#pragma unroll
        for (int q = 0; q < 4; q++)
            if (v_[q]) parts[base[g_[q]] + r_[q]] =
                make_float2(__int_as_float(s_[q]), w_[q]);
        __syncthreads();
        if (t < GMAX) base[t] += rk[t];
        __syncthreads();
    }
}

// t1 = emb @ W1  (17 x 128)
__global__ void k_t1(const float* __restrict__ emb, const float* __restrict__ W1,
                     float* __restrict__ t1) {
    int t = blockIdx.x, f = threadIdx.x;
    float acc = 0.f;
    for (int k = 0; k < DDIM; k++) acc += emb[t * DDIM + k] * W1[k * DDIM + f];
    t1[t * DDIM + f] = acc;
}

// x1[i] = relu(b1 + dinv_i*(sum_t C[i][t]*t1[t] + dinv_i*t1[ti]))  -> bf16x2
__global__ void __launch_bounds__(256) k_x1(
        const float2* __restrict__ nd, const float* __restrict__ Crep,
        const float* __restrict__ t1, const float* __restrict__ b1,
        uint* __restrict__ x1u, int N) {
    int lane = threadIdx.x & 63, wave = threadIdx.x >> 6;
    int i = blockIdx.x * 4 + wave;
    if (i >= N) return;
    float2 ndi = nd[i];
    float dinv_i = ndi.x;
    int ti = __float_as_int(ndi.y);
    const float* C0 = Crep + (size_t)i * CPAD;
    const float* C1 = Crep + ((size_t)N + i) * CPAD;
    float cc[17];
#pragma unroll
    for (int t = 0; t < 17; t++) cc[t] = C0[t] + C1[t];
    float ax = dinv_i * t1[ti * DDIM + lane];
    float ay = dinv_i * t1[ti * DDIM + 64 + lane];
#pragma unroll
    for (int t = 0; t < 17; t++) {
        ax += cc[t] * t1[t * DDIM + lane];
        ay += cc[t] * t1[t * DDIM + 64 + lane];
    }
    float vx = b1[lane]      + dinv_i * ax;
    float vy = b1[64 + lane] + dinv_i * ay;
    vx = vx > 0.f ? vx : 0.f;
    vy = vy > 0.f ? vy : 0.f;
    x1u[i * 64 + lane] = packbf(vx, vy);
}

// conv2+pool: block owns one (graph, slice); register accumulation;
// 16-wide gathers in flight.
__global__ void __launch_bounds__(256) k_conv2g(
        const float2* __restrict__ parts, const int* __restrict__ gStart,
        const uint* __restrict__ x1u, float* __restrict__ poolY) {
    __shared__ float2 meta[4][64];
    __shared__ float red[4][DDIM];
    int t = threadIdx.x, lane = t & 63, wave = t >> 6;
    int g = blockIdx.x / SLICES, sl = blockIdx.x % SLICES;
    int a = gStart[g], bnd = gStart[g + 1];
    long long len = bnd - a;
    int s0 = a + (int)(len * sl / SLICES);
    int s1 = a + (int)(len * (sl + 1) / SLICES);
    float ax = 0.f, ay = 0.f;
    for (int cb = s0 + wave * 64; cb < s1; cb += 4 * 64) {
        int idx = cb + lane;
        float2 m = (idx < s1) ? parts[idx] : make_float2(__int_as_float(0), 0.f);
        meta[wave][lane] = m;   // within-wave LDS write->read (lgkm ordered)
#pragma unroll
        for (int jj = 0; jj < 64; jj += 16) {
            float2 mm[16]; uint vv[16];
#pragma unroll
            for (int k = 0; k < 16; k++) mm[k] = meta[wave][jj + k];
#pragma unroll
            for (int k = 0; k < 16; k++)
                vv[k] = x1u[__float_as_int(mm[k].x) * 64 + lane];
#pragma unroll
            for (int k = 0; k < 16; k++) {
                ax += mm[k].y * bflo(vv[k]);
                ay += mm[k].y * bfhi(vv[k]);
            }
        }
    }
    red[wave][lane] = ax;
    red[wave][64 + lane] = ay;
    __syncthreads();
    if (wave == 0) {
        float vx = red[0][lane] + red[1][lane] + red[2][lane] + red[3][lane];
        float vy = red[0][64 + lane] + red[1][64 + lane] + red[2][64 + lane] + red[3][64 + lane];
        atomicAdd(&poolY[g * DDIM + lane], vx);
        atomicAdd(&poolY[g * DDIM + 64 + lane], vy);
    }
}

// out[g] = b2 + (poolY[g]/cnt[g]) @ W2 ; cnt from gBound
__global__ void __launch_bounds__(128) k_out(
        const float* __restrict__ poolY, const int* __restrict__ gBound,
        const float* __restrict__ W2, const float* __restrict__ b2,
        float* __restrict__ out) {
    __shared__ float py[DDIM];
    int g = blockIdx.x, f = threadIdx.x;
    py[f] = poolY[g * DDIM + f];
    __syncthreads();
    float acc = 0.f;
    for (int k = 0; k < DDIM; k++) acc += py[k] * W2[k * DDIM + f];
    int c = gBound[g + 1] - gBound[g];
    out[g * DDIM + f] = (c > 0) ? (b2[f] + acc / (float)c) : 0.f;
}

extern "C" void kernel_launch(void* const* d_in, const int* in_sizes, int n_in,
                              void* d_out, int out_size, void* d_ws, size_t ws_size,
                              hipStream_t stream) {
    const int* node_ids = (const int*)d_in[0];
    const int* edge_index = (const int*)d_in[1];
    const int* batch = (const int*)d_in[2];
    const float* emb = (const float*)d_in[4];
    const float* W1 = (const float*)d_in[5];
    const float* b1 = (const float*)d_in[6];
    const float* W2 = (const float*)d_in[7];
    const float* b2 = (const float*)d_in[8];
    float* out = (float*)d_out;

    const int N = in_sizes[0];
    const int E = in_sizes[1] / 2;
    const int M = E + N;
    const int* src = edge_index;
    const int* dst = edge_index + E;

    char* ws = (char*)d_ws;
    size_t off = 0;
    auto carve = [&](size_t bytes) { char* p = ws + off; off = (off + bytes + 255) & ~size_t(255); return p; };
    uint*   x1u       = (uint*)carve((size_t)N * 64 * 4);       // bf16x2 packed
    float2* parts     = (float2*)carve((size_t)M * 8);          // {src bits, w}
    float*  Crep      = (float*)carve((size_t)2 * N * CPAD * 4);// bins+deg, 2 replicas
    float2* nd        = (float2*)carve((size_t)N * 8);
    int*    blockHist = (int*)carve((size_t)NPB * GMAX * 4);
    int*    localBase = (int*)carve((size_t)NPB * GMAX * 4);
    int*    tot       = (int*)carve(GMAX * 4);
    int*    gStart    = (int*)carve((GMAX + 1) * 4);
    int*    gBound    = (int*)carve((GMAX + 1) * 4);
    float*  t1        = (float*)carve(17 * DDIM * 4);
    float*  poolY     = (float*)carve((size_t)GMAX * DDIM * 4);

    hipMemsetAsync(Crep,  0, (size_t)2 * N * CPAD * 4, stream);
    hipMemsetAsync(poolY, 0, (size_t)GMAX * DDIM * 4, stream);

    k_gb<<<1, 128, 0, stream>>>(batch, gBound, N);
    k_p1<<<NPB, 256, 0, stream>>>(dst, gBound, Crep, blockHist, E, M, N);
    k_scanG<<<GMAX, 256, 0, stream>>>(blockHist, localBase, tot);
    k_scanT<<<1, 64, 0, stream>>>(tot, gStart);
    k_pack<<<(N + 255) / 256, 256, 0, stream>>>(Crep, node_ids, nd, N);
    k_partbin<<<NPB, 256, 0, stream>>>(src, dst, gBound, nd, localBase, gStart,
                                       parts, Crep, E, M, N);

    k_t1<<<17, DDIM, 0, stream>>>(emb, W1, t1);
    k_x1<<<(N + 3) / 4, 256, 0, stream>>>(nd, Crep, t1, b1, x1u, N);
    k_conv2g<<<GMAX * SLICES, 256, 0, stream>>>(parts, gStart, x1u, poolY);
    k_out<<<GMAX, 128, 0, stream>>>(poolY, gBound, W2, b2, out);
}

// Round 11
// 369.994 us; speedup vs baseline: 1.0509x; 1.0509x over previous
//
#include <hip/hip_runtime.h>
#include <hip/hip_bf16.h>

// GCN: x=emb[ids]; x1=relu(GCNConv(x,W1,b1)); y=Ahat@x1; out[g]=b2+(mean_g y)@W2
//
// Structure (R11):
//  - conv1: rank-17 input -> t1=(emb@W1); per-node 17 type bins C (edge atomics)
//    then dense 17-term FMA -> x1 (bf16x2, lane holds feats {lane, lane+64}).
//  - conv2+pool edge-parallel: items (E edges + N self loops) partitioned BY
//    GRAPH (two-pass deterministic), per-graph register accumulation.
//  - R11a: conv2g XCD swizzle. Old FETCH ~200MB = 8 x |x1|: a graph's 32
//    slice-blocks are consecutive ids -> round-robin dispatch spreads them
//    over all 8 XCDs, each fetching the graph's 400KB row range. Swizzle
//    g=(b&7)*8+((b>>3)>>5) pins all slices of a graph to one XCD.
//  - R11b: partbin writes parts via LDS reorder (chunk sorted by graph using
//    the deterministic ranks) -> coalesced run writes, not 1.7M 8B scatters.
//  - R11c: revert R10 Crep/deg-folding (no effect on partbin; hurt p1
//    locality). deg = int[N], C single copy.

#define DDIM 128
#define CPAD 20      // C row stride (17 used; 80 B keeps float4 alignment)
#define GMAX 64
#define NPB  2048    // partition blocks (fixed item ranges)
#define SLICES 32    // conv2 blocks per graph
typedef unsigned int uint;

__device__ __forceinline__ float bflo(uint v) { return __uint_as_float(v << 16); }
__device__ __forceinline__ float bfhi(uint v) { return __uint_as_float(v & 0xffff0000u); }
__device__ __forceinline__ uint packbf(float x, float y) {  // RNE round both
    uint ux = __float_as_uint(x), uy = __float_as_uint(y);
    ux = (ux + 0x7fff + ((ux >> 16) & 1)) >> 16;
    uy = (uy + 0x7fff + ((uy >> 16) & 1)) & 0xffff0000u;
    return ux | uy;
}

// gBound[g] = first node index with batch >= g (batch sorted). 65 entries.
__global__ void k_gb(const int* __restrict__ batch, int* __restrict__ gBound, int N) {
    int g = threadIdx.x;
    if (g > GMAX) return;
    int lo = 0, hi = N;
    while (lo < hi) {
        int mid = (lo + hi) >> 1;
        if (batch[mid] < g) lo = mid + 1; else hi = mid;
    }
    gBound[g] = lo;
}

// Pass 1: deg atomics + per-block per-graph histogram (graph via LDS bsearch).
__global__ void __launch_bounds__(256) k_p1(
        const int* __restrict__ dst, const int* __restrict__ gBound,
        int* __restrict__ deg, int* __restrict__ blockHist, int E, int M) {
    __shared__ int h[4][GMAX];
    __shared__ int gb[GMAX + 1];
    int t = threadIdx.x, wave = t >> 6;
    if ((t & 63) < GMAX) h[wave][t & 63] = 0;
    if (t <= GMAX) gb[t] = gBound[t];
    __syncthreads();
    int per = (M + NPB - 1) / NPB;
    int lo = blockIdx.x * per;
    int hi = lo + per; if (hi > M) hi = M;
    for (int cb = lo; cb < hi; cb += 1024) {
        int idx_[4]; bool v_[4], isE_[4];
#pragma unroll
        for (int q = 0; q < 4; q++) {
            int item = cb + q * 256 + t;
            v_[q] = item < hi;
            isE_[q] = item < E;
            idx_[q] = 0;
            if (v_[q]) idx_[q] = isE_[q] ? dst[item] : (item - E);
        }
#pragma unroll
        for (int q = 0; q < 4; q++) {
            if (v_[q]) {
                int idx = idx_[q];
                int glo = 0, ghi = GMAX - 1;
#pragma unroll
                for (int it2 = 0; it2 < 6; it2++) {
                    int mid = (glo + ghi + 1) >> 1;
                    if (gb[mid] <= idx) glo = mid; else ghi = mid - 1;
                }
                if (isE_[q]) atomicAdd(&deg[idx], 1);
                atomicAdd(&h[wave][glo], 1);
            }
        }
    }
    __syncthreads();
    if (t < GMAX)
        blockHist[blockIdx.x * GMAX + t] = h[0][t] + h[1][t] + h[2][t] + h[3][t];
}

// Per-graph parallel exclusive scan over NPB block histograms.
__global__ void __launch_bounds__(256) k_scanG(
        const int* __restrict__ blockHist, int* __restrict__ localBase,
        int* __restrict__ tot) {
    __shared__ int sm[256];
    int g = blockIdx.x, t = threadIdx.x;
    const int PER = NPB / 256;     // 8
    int v[PER], loc[PER];
    int run = 0;
#pragma unroll
    for (int q = 0; q < PER; q++) {
        v[q] = blockHist[(t * PER + q) * GMAX + g];
        loc[q] = run;
        run += v[q];
    }
    sm[t] = run; __syncthreads();
    for (int off = 1; off < 256; off <<= 1) {
        int a = (t >= off) ? sm[t - off] : 0;
        __syncthreads();
        sm[t] += a; __syncthreads();
    }
    int excl = sm[t] - run;
#pragma unroll
    for (int q = 0; q < PER; q++)
        localBase[(t * PER + q) * GMAX + g] = excl + loc[q];
    if (t == 255) tot[g] = sm[255];
}

__global__ void k_scanT(const int* __restrict__ tot, int* __restrict__ gStart) {
    if (threadIdx.x == 0) {
        int run = 0;
        for (int g = 0; g < GMAX; g++) { gStart[g] = run; run += tot[g]; }
        gStart[GMAX] = run;
    }
}

// nd[i] = {dinv_i, type_i bits}
__global__ void k_pack(const int* __restrict__ deg, const int* __restrict__ ids,
                       float2* __restrict__ nd, int N) {
    int i = blockIdx.x * blockDim.x + threadIdx.x;
    if (i < N) {
        float dinv = rsqrtf((float)(deg[i] + 1));
        nd[i] = make_float2(dinv, __int_as_float(ids[i]));
    }
}

// Pass 2: partition items into parts[]={src bits, w} by graph (LDS-reordered
// coalesced run writes) AND accumulate conv1 bins C[d][type_s] += dinv_s.
__global__ void __launch_bounds__(256) k_partbin(
        const int* __restrict__ src, const int* __restrict__ dst,
        const int* __restrict__ gBound, const float2* __restrict__ nd,
        const int* __restrict__ localBase, const int* __restrict__ gStart,
        float2* __restrict__ parts, float* __restrict__ C, int E, int M) {
    __shared__ int rk[GMAX];
    __shared__ int runOff[GMAX + 1];
    __shared__ int base[GMAX];
    __shared__ int gb[GMAX + 1];
    __shared__ float2 sbuf[1024];          // chunk sorted by graph
    int t = threadIdx.x, b = blockIdx.x;
    if (t < GMAX) base[t] = gStart[t] + localBase[b * GMAX + t];
    if (t <= GMAX) gb[t] = gBound[t];
    int per = (M + NPB - 1) / NPB;
    int lo = b * per;
    int hi = lo + per; if (hi > M) hi = M;
    for (int cb = lo; cb < hi; cb += 1024) {
        int cnt = hi - cb; if (cnt > 1024) cnt = 1024;
        if (t < GMAX) rk[t] = 0;
        __syncthreads();
        int s_[4], g_[4], r_[4], d_[4]; float w_[4]; bool v_[4], isE_[4];
#pragma unroll
        for (int q = 0; q < 4; q++) {            // batched independent loads
            int item = cb + q * 256 + t;
            v_[q] = item < hi;
            isE_[q] = item < E;
            s_[q] = 0; d_[q] = 0; g_[q] = 0; r_[q] = 0; w_[q] = 0.f;
            if (v_[q]) {
                if (isE_[q]) { s_[q] = src[item]; d_[q] = dst[item]; }
                else         { s_[q] = item - E;  d_[q] = item - E; }
            }
        }
#pragma unroll
        for (int q = 0; q < 4; q++) {            // gathers batched in flight
            if (v_[q]) {
                int idx = d_[q];
                int glo = 0, ghi = GMAX - 1;
#pragma unroll
                for (int it2 = 0; it2 < 6; it2++) {
                    int mid = (glo + ghi + 1) >> 1;
                    if (gb[mid] <= idx) glo = mid; else ghi = mid - 1;
                }
                g_[q] = glo;
                float2 ns = nd[s_[q]];
                float dd = nd[d_[q]].x;
                w_[q] = ns.x * dd;
                if (isE_[q])                     // conv1 bin (fire-and-forget)
                    atomicAdd(&C[d_[q] * CPAD + __float_as_int(ns.y)], ns.x);
                r_[q] = atomicAdd(&rk[g_[q]], 1);
            }
        }
        __syncthreads();
        if (t == 0) {                            // tiny 64-entry scan
            int run = 0;
#pragma unroll
            for (int g = 0; g < GMAX; g++) { runOff[g] = run; run += rk[g]; }
            runOff[GMAX] = run;
        }
        __syncthreads();
#pragma unroll
        for (int q = 0; q < 4; q++)              // LDS scatter: sort by graph
            if (v_[q]) sbuf[runOff[g_[q]] + r_[q]] =
                make_float2(__uint_as_float((uint)s_[q] | ((uint)g_[q] << 20)), w_[q]);
        __syncthreads();
#pragma unroll
        for (int q = 0; q < 4; q++) {            // coalesced run write-out
            int p = q * 256 + t;
            if (p < cnt) {
                float2 u = sbuf[p];
                uint pk = __float_as_uint(u.x);
                int g = pk >> 20;
                int s = pk & 0xFFFFF;
                parts[base[g] + (p - runOff[g])] =
                    make_float2(__int_as_float(s), u.y);
            }
        }
        __syncthreads();
        if (t < GMAX) base[t] += rk[t];
    }
}

// t1 = emb @ W1  (17 x 128)
__global__ void k_t1(const float* __restrict__ emb, const float* __restrict__ W1,
                     float* __restrict__ t1) {
    int t = blockIdx.x, f = threadIdx.x;
    float acc = 0.f;
    for (int k = 0; k < DDIM; k++) acc += emb[t * DDIM + k] * W1[k * DDIM + f];
    t1[t * DDIM + f] = acc;
}

// x1[i] = relu(b1 + dinv_i*(sum_t C[i][t]*t1[t] + dinv_i*t1[ti]))  -> bf16x2
__global__ void __launch_bounds__(256) k_x1(
        const float2* __restrict__ nd, const float* __restrict__ C,
        const float* __restrict__ t1, const float* __restrict__ b1,
        uint* __restrict__ x1u, int N) {
    int lane = threadIdx.x & 63, wave = threadIdx.x >> 6;
    int i = blockIdx.x * 4 + wave;
    if (i >= N) return;
    float2 ndi = nd[i];
    float dinv_i = ndi.x;
    int ti = __float_as_int(ndi.y);
    const float4* Cv = (const float4*)(C + i * CPAD);
    float4 c0 = Cv[0], c1 = Cv[1], c2 = Cv[2], c3 = Cv[3];
    float c16 = C[i * CPAD + 16];
    float cc[17] = {c0.x, c0.y, c0.z, c0.w, c1.x, c1.y, c1.z, c1.w,
                    c2.x, c2.y, c2.z, c2.w, c3.x, c3.y, c3.z, c3.w, c16};
    float ax = dinv_i * t1[ti * DDIM + lane];
    float ay = dinv_i * t1[ti * DDIM + 64 + lane];
#pragma unroll
    for (int t = 0; t < 17; t++) {
        ax += cc[t] * t1[t * DDIM + lane];
        ay += cc[t] * t1[t * DDIM + 64 + lane];
    }
    float vx = b1[lane]      + dinv_i * ax;
    float vy = b1[64 + lane] + dinv_i * ay;
    vx = vx > 0.f ? vx : 0.f;
    vy = vy > 0.f ? vy : 0.f;
    x1u[i * 64 + lane] = packbf(vx, vy);
}

// conv2+pool: block owns one (graph, slice); register accumulation; 16-wide
// gathers. XCD swizzle: all 32 slices of a graph on one XCD (b%8), so the
// graph's contiguous x1 row range stays in that XCD's L2.
__global__ void __launch_bounds__(256) k_conv2g(
        const float2* __restrict__ parts, const int* __restrict__ gStart,
        const uint* __restrict__ x1u, float* __restrict__ poolY) {
    __shared__ float2 meta[4][64];
    __shared__ float red[4][DDIM];
    int t = threadIdx.x, lane = t & 63, wave = t >> 6;
    int b = blockIdx.x;
    int j = b >> 3;                       // per-XCD block index (round-robin)
    int g = (b & 7) * 8 + (j >> 5);       // 8 graphs per XCD
    int sl = j & 31;
    int a = gStart[g], bnd = gStart[g + 1];
    long long len = bnd - a;
    int s0 = a + (int)(len * sl / SLICES);
    int s1 = a + (int)(len * (sl + 1) / SLICES);
    float ax = 0.f, ay = 0.f;
    for (int cb = s0 + wave * 64; cb < s1; cb += 4 * 64) {
        int idx = cb + lane;
        float2 m = (idx < s1) ? parts[idx] : make_float2(__int_as_float(0), 0.f);
        meta[wave][lane] = m;   // within-wave LDS write->read (lgkm ordered)
#pragma unroll
        for (int jj = 0; jj < 64; jj += 16) {
            float2 mm[16]; uint vv[16];
#pragma unroll
            for (int k = 0; k < 16; k++) mm[k] = meta[wave][jj + k];
#pragma unroll
            for (int k = 0; k < 16; k++)
                vv[k] = x1u[__float_as_int(mm[k].x) * 64 + lane];
#pragma unroll
            for (int k = 0; k < 16; k++) {
                ax += mm[k].y * bflo(vv[k]);
                ay += mm[k].y * bfhi(vv[k]);
            }
        }
    }
    red[wave][lane] = ax;
    red[wave][64 + lane] = ay;
    __syncthreads();
    if (wave == 0) {
        float vx = red[0][lane] + red[1][lane] + red[2][lane] + red[3][lane];
        float vy = red[0][64 + lane] + red[1][64 + lane] + red[2][64 + lane] + red[3][64 + lane];
        atomicAdd(&poolY[g * DDIM + lane], vx);
        atomicAdd(&poolY[g * DDIM + 64 + lane], vy);
    }
}

// out[g] = b2 + (poolY[g]/cnt[g]) @ W2 ; cnt from gBound
__global__ void __launch_bounds__(128) k_out(
        const float* __restrict__ poolY, const int* __restrict__ gBound,
        const float* __restrict__ W2, const float* __restrict__ b2,
        float* __restrict__ out) {
    __shared__ float py[DDIM];
    int g = blockIdx.x, f = threadIdx.x;
    py[f] = poolY[g * DDIM + f];
    __syncthreads();
    float acc = 0.f;
    for (int k = 0; k < DDIM; k++) acc += py[k] * W2[k * DDIM + f];
    int c = gBound[g + 1] - gBound[g];
    out[g * DDIM + f] = (c > 0) ? (b2[f] + acc / (float)c) : 0.f;
}

extern "C" void kernel_launch(void* const* d_in, const int* in_sizes, int n_in,
                              void* d_out, int out_size, void* d_ws, size_t ws_size,
                              hipStream_t stream) {
    const int* node_ids = (const int*)d_in[0];
    const int* edge_index = (const int*)d_in[1];
    const int* batch = (const int*)d_in[2];
    const float* emb = (const float*)d_in[4];
    const float* W1 = (const float*)d_in[5];
    const float* b1 = (const float*)d_in[6];
    const float* W2 = (const float*)d_in[7];
    const float* b2 = (const float*)d_in[8];
    float* out = (float*)d_out;

    const int N = in_sizes[0];
    const int E = in_sizes[1] / 2;
    const int M = E + N;
    const int* src = edge_index;
    const int* dst = edge_index + E;

    char* ws = (char*)d_ws;
    size_t off = 0;
    auto carve = [&](size_t bytes) { char* p = ws + off; off = (off + bytes + 255) & ~size_t(255); return p; };
    uint*   x1u       = (uint*)carve((size_t)N * 64 * 4);     // bf16x2 packed
    float2* parts     = (float2*)carve((size_t)M * 8);        // {src bits, w}
    float*  C         = (float*)carve((size_t)N * CPAD * 4);  // type bins
    float2* nd        = (float2*)carve((size_t)N * 8);
    int*    deg       = (int*)carve((size_t)N * 4);
    int*    blockHist = (int*)carve((size_t)NPB * GMAX * 4);
    int*    localBase = (int*)carve((size_t)NPB * GMAX * 4);
    int*    tot       = (int*)carve(GMAX * 4);
    int*    gStart    = (int*)carve((GMAX + 1) * 4);
    int*    gBound    = (int*)carve((GMAX + 1) * 4);
    float*  t1        = (float*)carve(17 * DDIM * 4);
    float*  poolY     = (float*)carve((size_t)GMAX * DDIM * 4);

    hipMemsetAsync(deg,   0, (size_t)N * 4, stream);
    hipMemsetAsync(C,     0, (size_t)N * CPAD * 4, stream);
    hipMemsetAsync(poolY, 0, (size_t)GMAX * DDIM * 4, stream);

    k_gb<<<1, 128, 0, stream>>>(batch, gBound, N);
    k_p1<<<NPB, 256, 0, stream>>>(dst, gBound, deg, blockHist, E, M);
    k_scanG<<<GMAX, 256, 0, stream>>>(blockHist, localBase, tot);
    k_scanT<<<1, 64, 0, stream>>>(tot, gStart);
    k_pack<<<(N + 255) / 256, 256, 0, stream>>>(deg, node_ids, nd, N);
    k_partbin<<<NPB, 256, 0, stream>>>(src, dst, gBound, nd, localBase, gStart,
                                       parts, C, E, M);

    k_t1<<<17, DDIM, 0, stream>>>(emb, W1, t1);
    k_x1<<<(N + 3) / 4, 256, 0, stream>>>(nd, C, t1, b1, x1u, N);
    k_conv2g<<<GMAX * SLICES, 256, 0, stream>>>(parts, gStart, x1u, poolY);
    k_out<<<GMAX, 128, 0, stream>>>(poolY, gBound, W2, b2, out);
}

// Round 12
// 236.064 us; speedup vs baseline: 1.6472x; 1.5673x over previous
//
#include <hip/hip_runtime.h>
#include <hip/hip_bf16.h>

// GCN: x=emb[ids]; x1=relu(GCNConv(x,W1,b1)); y=Ahat@x1; out[g]=b2+(mean_g y)@W2
//
// Structure (R12): ZERO global atomics.
//  - Items (E edges + N self loops) partitioned into 512 dst-buckets (8 per
//    graph, graph-aligned so bucket-major == graph-major for conv2+pool).
//    parts key = {self(1)|dstLocal(8)|src(17)} packed uint.
//  - k_cnt2: per-bucket LDS count -> nd (deg) densely. No deg atomics.
//  - k_x1b: per-bucket conv1: gather nd[src], LDS bins CL[node][type]
//    (spread addresses - uncorrelated, unlike R6's 128 hot ones), dense
//    x1 = relu(b1 + dinv*(CL@t1 + dinv*t1[ti])); also writes conv2 weight
//    partsW coalesced. Replaces the 1.6M global-fp32-atomic pass that was
//    pinned at ~85us across R7-R11 (device RMW throughput floor).
//  - conv2+pool: per-(graph,slice) register accumulation, 16-wide gathers,
//    XCD swizzle.

#define DDIM 128
#define GMAX 64
#define BPG  8                 // buckets per graph
#define NBK  (GMAX * BPG)      // 512 buckets
#define NPB  2048              // partition blocks
#define SLICES 32              // conv2 blocks per graph
typedef unsigned int uint;
typedef unsigned short ushort;

__device__ __forceinline__ float bflo(uint v) { return __uint_as_float(v << 16); }
__device__ __forceinline__ float bfhi(uint v) { return __uint_as_float(v & 0xffff0000u); }
__device__ __forceinline__ uint packbf(float x, float y) {  // RNE round both
    uint ux = __float_as_uint(x), uy = __float_as_uint(y);
    ux = (ux + 0x7fff + ((ux >> 16) & 1)) >> 16;
    uy = (uy + 0x7fff + ((uy >> 16) & 1)) & 0xffff0000u;
    return ux | uy;
}

// gBound[65] (bsearch on sorted batch) and bkBound[513] (graph-aligned 8-way split)
__global__ void k_gb2(const int* __restrict__ batch, int N,
                      int* __restrict__ gBound, int* __restrict__ bkBound) {
    __shared__ int gB[GMAX + 1];
    int t = threadIdx.x;
    if (t <= GMAX) {
        int key = t, lo = 0, hi = N;
        while (lo < hi) {
            int mid = (lo + hi) >> 1;
            if (batch[mid] < key) lo = mid + 1; else hi = mid;
        }
        gB[t] = lo;
        gBound[t] = lo;
    }
    __syncthreads();
    for (int bk = t; bk <= NBK; bk += 256) {
        int v;
        if (bk == NBK) v = gB[GMAX];
        else {
            int g = bk >> 3, s = bk & 7;
            int A = gB[g], L = gB[g + 1] - A;
            v = A + (int)((long long)L * s / BPG);
        }
        bkBound[bk] = v;
    }
}

__device__ __forceinline__ int bksearch(const int* bkB, int idx) {
    int lo = 0, hi = NBK - 1;
#pragma unroll
    for (int it = 0; it < 9; it++) {           // 2^9 = 512
        int mid = (lo + hi + 1) >> 1;
        if (bkB[mid] <= idx) lo = mid; else hi = mid - 1;
    }
    return lo;
}

// Pass 1: per-block bucket histogram (no atomHBM work at all).
__global__ void __launch_bounds__(256) k_p1(
        const int* __restrict__ dst, const int* __restrict__ bkBound,
        int* __restrict__ blockHist, int E, int M) {
    __shared__ int h[NBK];
    __shared__ int bkB[NBK + 1];
    int t = threadIdx.x;
    for (int k = t; k < NBK; k += 256) h[k] = 0;
    for (int k = t; k <= NBK; k += 256) bkB[k] = bkBound[k];
    __syncthreads();
    int per = (M + NPB - 1) / NPB;
    int lo = blockIdx.x * per;
    int hi = lo + per; if (hi > M) hi = M;
    for (int cb = lo; cb < hi; cb += 1024) {
        int idx_[4]; bool v_[4];
#pragma unroll
        for (int q = 0; q < 4; q++) {
            int item = cb + q * 256 + t;
            v_[q] = item < hi;
            idx_[q] = 0;
            if (v_[q]) idx_[q] = (item < E) ? dst[item] : (item - E);
        }
#pragma unroll
        for (int q = 0; q < 4; q++)
            if (v_[q]) atomicAdd(&h[bksearch(bkB, idx_[q])], 1);
    }
    __syncthreads();
    for (int k = t; k < NBK; k += 256) blockHist[blockIdx.x * NBK + k] = h[k];
}

// Per-bucket exclusive scan over NPB block histograms.
__global__ void __launch_bounds__(256) k_scanG(
        const int* __restrict__ blockHist, int* __restrict__ localBase,
        int* __restrict__ tot) {
    __shared__ int sm[256];
    int g = blockIdx.x, t = threadIdx.x;
    const int PER = NPB / 256;     // 8
    int v[PER], loc[PER];
    int run = 0;
#pragma unroll
    for (int q = 0; q < PER; q++) {
        v[q] = blockHist[(t * PER + q) * NBK + g];
        loc[q] = run;
        run += v[q];
    }
    sm[t] = run; __syncthreads();
    for (int off = 1; off < 256; off <<= 1) {
        int a = (t >= off) ? sm[t - off] : 0;
        __syncthreads();
        sm[t] += a; __syncthreads();
    }
    int excl = sm[t] - run;
#pragma unroll
    for (int q = 0; q < PER; q++)
        localBase[(t * PER + q) * NBK + g] = excl + loc[q];
    if (t == 255) tot[g] = sm[255];
}

// bkStart[513] from tot[512] (one block, pair scan)
__global__ void __launch_bounds__(256) k_scanT(
        const int* __restrict__ tot, int* __restrict__ bkStart) {
    __shared__ int sm[256];
    int t = threadIdx.x;
    int v0 = tot[2 * t], v1 = tot[2 * t + 1];
    int run = v0 + v1;
    sm[t] = run; __syncthreads();
    for (int off = 1; off < 256; off <<= 1) {
        int a = (t >= off) ? sm[t - off] : 0;
        __syncthreads();
        sm[t] += a; __syncthreads();
    }
    int excl = sm[t] - run;
    bkStart[2 * t] = excl;
    bkStart[2 * t + 1] = excl + v0;
    if (t == 255) bkStart[NBK] = sm[255];
}

// Pass 2: scatter packed keys {self|dstLocal|src} into bucket-major parts.
__global__ void __launch_bounds__(256) k_part(
        const int* __restrict__ src, const int* __restrict__ dst,
        const int* __restrict__ bkBound, const int* __restrict__ localBase,
        const int* __restrict__ bkStart, uint* __restrict__ partsKey,
        int E, int M) {
    __shared__ int rk[NBK];
    __shared__ int runOff[NBK];
    __shared__ int base[NBK];
    __shared__ int bkB[NBK + 1];
    __shared__ uint sbuf[1024];
    __shared__ ushort sb2[1024];
    __shared__ int sms[256];
    int t = threadIdx.x, b = blockIdx.x;
    for (int k = t; k < NBK; k += 256) base[k] = bkStart[k] + localBase[b * NBK + k];
    for (int k = t; k <= NBK; k += 256) bkB[k] = bkBound[k];
    int per = (M + NPB - 1) / NPB;
    int lo = b * per;
    int hi = lo + per; if (hi > M) hi = M;
    for (int cb = lo; cb < hi; cb += 1024) {
        int cnt = hi - cb; if (cnt > 1024) cnt = 1024;
        for (int k = t; k < NBK; k += 256) rk[k] = 0;
        __syncthreads();
        uint key_[4]; int bk_[4], r_[4]; bool v_[4];
#pragma unroll
        for (int q = 0; q < 4; q++) {              // batched coalesced loads
            int item = cb + q * 256 + t;
            v_[q] = item < hi;
            key_[q] = 0; bk_[q] = 0; r_[q] = 0;
            if (v_[q]) {
                int s, d; uint selfBit;
                if (item < E) { s = src[item]; d = dst[item]; selfBit = 0u; }
                else          { s = item - E;  d = s; selfBit = 1u << 25; }
                int bk = bksearch(bkB, d);
                bk_[q] = bk;
                key_[q] = selfBit | ((uint)(d - bkB[bk]) << 17) | (uint)s;
            }
        }
#pragma unroll
        for (int q = 0; q < 4; q++)
            if (v_[q]) r_[q] = atomicAdd(&rk[bk_[q]], 1);
        __syncthreads();
        {   // pair-scan rk[512] -> runOff (exclusive)
            int v0 = rk[2 * t], v1 = rk[2 * t + 1];
            int run = v0 + v1;
            sms[t] = run; __syncthreads();
            for (int off = 1; off < 256; off <<= 1) {
                int a = (t >= off) ? sms[t - off] : 0;
                __syncthreads();
                sms[t] += a; __syncthreads();
            }
            int excl = sms[t] - run;
            runOff[2 * t] = excl;
            runOff[2 * t + 1] = excl + v0;
        }
        __syncthreads();
#pragma unroll
        for (int q = 0; q < 4; q++)                // LDS sort by bucket
            if (v_[q]) {
                int p = runOff[bk_[q]] + r_[q];
                sbuf[p] = key_[q];
                sb2[p] = (ushort)bk_[q];
            }
        __syncthreads();
#pragma unroll
        for (int q = 0; q < 4; q++) {              // coalesced run write-out
            int p = q * 256 + t;
            if (p < cnt) {
                int bk = sb2[p];
                partsKey[base[bk] + (p - runOff[bk])] = sbuf[p];
            }
        }
        __syncthreads();
        for (int k = t; k < NBK; k += 256) base[k] += rk[k];
        __syncthreads();
    }
}

// Per-bucket: count dstLocal -> nd (dinv, type) densely. No atomics to HBM.
__global__ void __launch_bounds__(256) k_cnt2(
        const uint* __restrict__ partsKey, const int* __restrict__ bkBound,
        const int* __restrict__ bkStart, const int* __restrict__ ids,
        float2* __restrict__ nd) {
    __shared__ int cnt[256];
    int b = blockIdx.x, t = threadIdx.x;
    cnt[t] = 0;
    __syncthreads();
    int lo = bkStart[b], hi = bkStart[b + 1];
    for (int idx = lo + t; idx < hi; idx += 256) {
        uint key = partsKey[idx];
        if (!(key >> 25)) atomicAdd(&cnt[(key >> 17) & 0xFF], 1);
    }
    __syncthreads();
    int nodeLo = bkBound[b], nn = bkBound[b + 1] - nodeLo;
    if (t < nn) {
        int i = nodeLo + t;
        nd[i] = make_float2(rsqrtf((float)(cnt[t] + 1)),
                            __int_as_float(ids[i]));
    }
}

// t1 = emb @ W1  (17 x 128)
__global__ void k_t1(const float* __restrict__ emb, const float* __restrict__ W1,
                     float* __restrict__ t1) {
    int t = blockIdx.x, f = threadIdx.x;
    float acc = 0.f;
    for (int k = 0; k < DDIM; k++) acc += emb[t * DDIM + k] * W1[k * DDIM + f];
    t1[t * DDIM + f] = acc;
}

// Per-bucket conv1 + conv2-weight: LDS bins CL[node][type] (spread addresses),
// dense x1 compute, coalesced partsW write.
__global__ void __launch_bounds__(256) k_x1b(
        const uint* __restrict__ partsKey, const int* __restrict__ bkBound,
        const int* __restrict__ bkStart, const float2* __restrict__ nd,
        const float* __restrict__ t1, const float* __restrict__ b1,
        float* __restrict__ partsW, uint* __restrict__ x1u) {
    __shared__ float t1s[17 * DDIM];    // 8.7 KB
    __shared__ float CL[256 * 17];      // 17.4 KB
    __shared__ float2 ndL[256];
    __shared__ float bL[DDIM];
    int b = blockIdx.x, t = threadIdx.x;
    int nodeLo = bkBound[b], nn = bkBound[b + 1] - nodeLo;
    for (int k = t; k < 17 * DDIM; k += 256) t1s[k] = t1[k];
    for (int k = t; k < 256 * 17; k += 256) CL[k] = 0.f;
    if (t < DDIM) bL[t] = b1[t];
    if (t < nn) ndL[t] = nd[nodeLo + t];
    __syncthreads();
    int lo = bkStart[b], hi = bkStart[b + 1];
    for (int cb = lo; cb < hi; cb += 1024) {
        uint key_[4]; bool v_[4];
#pragma unroll
        for (int q = 0; q < 4; q++) {
            int idx = cb + q * 256 + t;
            v_[q] = idx < hi;
            key_[q] = v_[q] ? partsKey[idx] : 0u;
        }
#pragma unroll
        for (int q = 0; q < 4; q++) {
            if (v_[q]) {
                uint key = key_[q];
                int s = key & 0x1FFFF;
                int dL = (key >> 17) & 0xFF;
                float2 ns = nd[s];                 // random 8B gather (batched)
                float w;
                if (key >> 25) {                   // self loop: w = dinv^2
                    w = ns.x * ns.x;
                } else {
                    w = ns.x * ndL[dL].x;
                    atomicAdd(&CL[dL * 17 + __float_as_int(ns.y)], ns.x);
                }
                partsW[cb + q * 256 + t] = w;      // coalesced
            }
        }
    }
    __syncthreads();
    int lane = t & 63, wave = t >> 6;
    for (int n = wave; n < nn; n += 4) {
        float dinv = ndL[n].x;
        int ti = __float_as_int(ndL[n].y);
        float ax = dinv * t1s[ti * DDIM + lane];
        float ay = dinv * t1s[ti * DDIM + 64 + lane];
#pragma unroll
        for (int tt = 0; tt < 17; tt++) {
            float c = CL[n * 17 + tt];
            ax += c * t1s[tt * DDIM + lane];
            ay += c * t1s[tt * DDIM + 64 + lane];
        }
        float vx = bL[lane]      + dinv * ax;
        float vy = bL[64 + lane] + dinv * ay;
        vx = vx > 0.f ? vx : 0.f;
        vy = vy > 0.f ? vy : 0.f;
        x1u[(nodeLo + n) * 64 + lane] = packbf(vx, vy);
    }
}

// conv2+pool: block owns one (graph, slice); register accumulation; 16-wide
// gathers; XCD swizzle (all 32 slices of a graph on one XCD).
__global__ void __launch_bounds__(256) k_conv2g(
        const uint* __restrict__ partsKey, const float* __restrict__ partsW,
        const int* __restrict__ bkStart, const uint* __restrict__ x1u,
        float* __restrict__ poolY) {
    __shared__ uint  mk[4][64];
    __shared__ float mw[4][64];
    __shared__ float red[4][DDIM];
    int t = threadIdx.x, lane = t & 63, wave = t >> 6;
    int b = blockIdx.x;
    int j = b >> 3;
    int g = (b & 7) * 8 + (j >> 5);
    int sl = j & 31;
    int a = bkStart[g * BPG], bnd = bkStart[(g + 1) * BPG];
    long long len = bnd - a;
    int s0 = a + (int)(len * sl / SLICES);
    int s1 = a + (int)(len * (sl + 1) / SLICES);
    float ax = 0.f, ay = 0.f;
    for (int cb = s0 + wave * 64; cb < s1; cb += 4 * 64) {
        int idx = cb + lane;
        mk[wave][lane] = (idx < s1) ? partsKey[idx] : 0u;
        mw[wave][lane] = (idx < s1) ? partsW[idx] : 0.f;
#pragma unroll
        for (int jj = 0; jj < 64; jj += 16) {
            uint kk[16]; float ww[16]; uint vv[16];
#pragma unroll
            for (int k = 0; k < 16; k++) { kk[k] = mk[wave][jj + k]; ww[k] = mw[wave][jj + k]; }
#pragma unroll
            for (int k = 0; k < 16; k++)
                vv[k] = x1u[(size_t)(kk[k] & 0x1FFFF) * 64 + lane];
#pragma unroll
            for (int k = 0; k < 16; k++) {
                ax += ww[k] * bflo(vv[k]);
                ay += ww[k] * bfhi(vv[k]);
            }
        }
    }
    red[wave][lane] = ax;
    red[wave][64 + lane] = ay;
    __syncthreads();
    if (wave == 0) {
        float vx = red[0][lane] + red[1][lane] + red[2][lane] + red[3][lane];
        float vy = red[0][64 + lane] + red[1][64 + lane] + red[2][64 + lane] + red[3][64 + lane];
        atomicAdd(&poolY[g * DDIM + lane], vx);
        atomicAdd(&poolY[g * DDIM + 64 + lane], vy);
    }
}

// out[g] = b2 + (poolY[g]/cnt[g]) @ W2 ; cnt from gBound
__global__ void __launch_bounds__(128) k_out(
        const float* __restrict__ poolY, const int* __restrict__ gBound,
        const float* __restrict__ W2, const float* __restrict__ b2,
        float* __restrict__ out) {
    __shared__ float py[DDIM];
    int g = blockIdx.x, f = threadIdx.x;
    py[f] = poolY[g * DDIM + f];
    __syncthreads();
    float acc = 0.f;
    for (int k = 0; k < DDIM; k++) acc += py[k] * W2[k * DDIM + f];
    int c = gBound[g + 1] - gBound[g];
    out[g * DDIM + f] = (c > 0) ? (b2[f] + acc / (float)c) : 0.f;
}

extern "C" void kernel_launch(void* const* d_in, const int* in_sizes, int n_in,
                              void* d_out, int out_size, void* d_ws, size_t ws_size,
                              hipStream_t stream) {
    const int* node_ids = (const int*)d_in[0];
    const int* edge_index = (const int*)d_in[1];
    const int* batch = (const int*)d_in[2];
    const float* emb = (const float*)d_in[4];
    const float* W1 = (const float*)d_in[5];
    const float* b1 = (const float*)d_in[6];
    const float* W2 = (const float*)d_in[7];
    const float* b2 = (const float*)d_in[8];
    float* out = (float*)d_out;

    const int N = in_sizes[0];
    const int E = in_sizes[1] / 2;
    const int M = E + N;
    const int* src = edge_index;
    const int* dst = edge_index + E;

    char* ws = (char*)d_ws;
    size_t off = 0;
    auto carve = [&](size_t bytes) { char* p = ws + off; off = (off + bytes + 255) & ~size_t(255); return p; };
    uint*   x1u       = (uint*)carve((size_t)N * 64 * 4);      // bf16x2 packed
    uint*   partsKey  = (uint*)carve((size_t)M * 4);           // self|dstLocal|src
    float*  partsW    = (float*)carve((size_t)M * 4);          // conv2 weights
    float2* nd        = (float2*)carve((size_t)N * 8);
    int*    blockHist = (int*)carve((size_t)NPB * NBK * 4);    // 4.2 MB
    int*    localBase = (int*)carve((size_t)NPB * NBK * 4);    // 4.2 MB
    int*    tot       = (int*)carve(NBK * 4);
    int*    bkStart   = (int*)carve((NBK + 1) * 4);
    int*    gBound    = (int*)carve((GMAX + 1) * 4);
    int*    bkBound   = (int*)carve((NBK + 1) * 4);
    float*  t1        = (float*)carve(17 * DDIM * 4);
    float*  poolY     = (float*)carve((size_t)GMAX * DDIM * 4);

    hipMemsetAsync(poolY, 0, (size_t)GMAX * DDIM * 4, stream);

    k_gb2<<<1, 256, 0, stream>>>(batch, N, gBound, bkBound);
    k_p1<<<NPB, 256, 0, stream>>>(dst, bkBound, blockHist, E, M);
    k_scanG<<<NBK, 256, 0, stream>>>(blockHist, localBase, tot);
    k_scanT<<<1, 256, 0, stream>>>(tot, bkStart);
    k_part<<<NPB, 256, 0, stream>>>(src, dst, bkBound, localBase, bkStart,
                                    partsKey, E, M);
    k_cnt2<<<NBK, 256, 0, stream>>>(partsKey, bkBound, bkStart, node_ids, nd);
    k_t1<<<17, DDIM, 0, stream>>>(emb, W1, t1);
    k_x1b<<<NBK, 256, 0, stream>>>(partsKey, bkBound, bkStart, nd, t1, b1,
                                   partsW, x1u);
    k_conv2g<<<GMAX * SLICES, 256, 0, stream>>>(partsKey, partsW, bkStart, x1u, poolY);
    k_out<<<GMAX, 128, 0, stream>>>(poolY, gBound, W2, b2, out);
}

// Round 13
// 220.269 us; speedup vs baseline: 1.7653x; 1.0717x over previous
//
#include <hip/hip_runtime.h>
#include <hip/hip_bf16.h>

// GCN: x=emb[ids]; x1=relu(GCNConv(x,W1,b1)); y=Ahat@x1; out[g]=b2+(mean_g y)@W2
//
// Structure (R13): zero global atomics; fp8 row gather.
//  - Items (E edges + N self loops) partitioned into 512 dst-buckets (8 per
//    graph, graph-aligned). Key = {self(1)|dstLocalGraph(12)|src(17)}.
//  - conv1 per-bucket in LDS (bins CL[node][type]), dense x1 compute.
//  - R13: z[s] = dinv_s * x1[s] stored FP8 e4m3 (128 B/row, HW cvt): the
//    conv2 gather working set is the whole z (src is uniform-random, so no
//    XCD locality exists - R12 FETCH was 8 XCDs x full x1). Per-item weight
//    is now dinv_d only -> LDS table per graph; partsW stream deleted.
//  - conv2+pool: per-(graph,slice) register accumulation, 16-wide gathers.

#define DDIM 128
#define GMAX 64
#define BPG  8                 // buckets per graph
#define NBK  (GMAX * BPG)      // 512 buckets
#define NPB  2048              // partition blocks
#define SLICES 32              // conv2 blocks per graph
#define MAXGN 2048             // max nodes per graph (mean 1563, +12 sigma)
typedef unsigned int uint;
typedef unsigned short ushort;
typedef float v2f __attribute__((ext_vector_type(2)));

__device__ __forceinline__ uint packbf(float x, float y) {  // (kept for ref)
    uint ux = __float_as_uint(x), uy = __float_as_uint(y);
    ux = (ux + 0x7fff + ((ux >> 16) & 1)) >> 16;
    uy = (uy + 0x7fff + ((uy >> 16) & 1)) & 0xffff0000u;
    return ux | uy;
}

// gBound[65] (bsearch on sorted batch) and bkBound[513] (graph-aligned 8-way split)
__global__ void k_gb2(const int* __restrict__ batch, int N,
                      int* __restrict__ gBound, int* __restrict__ bkBound) {
    __shared__ int gB[GMAX + 1];
    int t = threadIdx.x;
    if (t <= GMAX) {
        int key = t, lo = 0, hi = N;
        while (lo < hi) {
            int mid = (lo + hi) >> 1;
            if (batch[mid] < key) lo = mid + 1; else hi = mid;
        }
        gB[t] = lo;
        gBound[t] = lo;
    }
    __syncthreads();
    for (int bk = t; bk <= NBK; bk += 256) {
        int v;
        if (bk == NBK) v = gB[GMAX];
        else {
            int g = bk >> 3, s = bk & 7;
            int A = gB[g], L = gB[g + 1] - A;
            v = A + (int)((long long)L * s / BPG);
        }
        bkBound[bk] = v;
    }
}

__device__ __forceinline__ int bksearch(const int* bkB, int idx) {
    int lo = 0, hi = NBK - 1;
#pragma unroll
    for (int it = 0; it < 9; it++) {           // 2^9 = 512
        int mid = (lo + hi + 1) >> 1;
        if (bkB[mid] <= idx) lo = mid; else hi = mid - 1;
    }
    return lo;
}

// Pass 1: per-block bucket histogram.
__global__ void __launch_bounds__(256) k_p1(
        const int* __restrict__ dst, const int* __restrict__ bkBound,
        int* __restrict__ blockHist, int E, int M) {
    __shared__ int h[NBK];
    __shared__ int bkB[NBK + 1];
    int t = threadIdx.x;
    for (int k = t; k < NBK; k += 256) h[k] = 0;
    for (int k = t; k <= NBK; k += 256) bkB[k] = bkBound[k];
    __syncthreads();
    int per = (M + NPB - 1) / NPB;
    int lo = blockIdx.x * per;
    int hi = lo + per; if (hi > M) hi = M;
    for (int cb = lo; cb < hi; cb += 1024) {
        int idx_[4]; bool v_[4];
#pragma unroll
        for (int q = 0; q < 4; q++) {
            int item = cb + q * 256 + t;
            v_[q] = item < hi;
            idx_[q] = 0;
            if (v_[q]) idx_[q] = (item < E) ? dst[item] : (item - E);
        }
#pragma unroll
        for (int q = 0; q < 4; q++)
            if (v_[q]) atomicAdd(&h[bksearch(bkB, idx_[q])], 1);
    }
    __syncthreads();
    for (int k = t; k < NBK; k += 256) blockHist[blockIdx.x * NBK + k] = h[k];
}

// Per-bucket exclusive scan over NPB block histograms.
__global__ void __launch_bounds__(256) k_scanG(
        const int* __restrict__ blockHist, int* __restrict__ localBase,
        int* __restrict__ tot) {
    __shared__ int sm[256];
    int g = blockIdx.x, t = threadIdx.x;
    const int PER = NPB / 256;     // 8
    int v[PER], loc[PER];
    int run = 0;
#pragma unroll
    for (int q = 0; q < PER; q++) {
        v[q] = blockHist[(t * PER + q) * NBK + g];
        loc[q] = run;
        run += v[q];
    }
    sm[t] = run; __syncthreads();
    for (int off = 1; off < 256; off <<= 1) {
        int a = (t >= off) ? sm[t - off] : 0;
        __syncthreads();
        sm[t] += a; __syncthreads();
    }
    int excl = sm[t] - run;
#pragma unroll
    for (int q = 0; q < PER; q++)
        localBase[(t * PER + q) * NBK + g] = excl + loc[q];
    if (t == 255) tot[g] = sm[255];
}

// bkStart[513] from tot[512]
__global__ void __launch_bounds__(256) k_scanT(
        const int* __restrict__ tot, int* __restrict__ bkStart) {
    __shared__ int sm[256];
    int t = threadIdx.x;
    int v0 = tot[2 * t], v1 = tot[2 * t + 1];
    int run = v0 + v1;
    sm[t] = run; __syncthreads();
    for (int off = 1; off < 256; off <<= 1) {
        int a = (t >= off) ? sm[t - off] : 0;
        __syncthreads();
        sm[t] += a; __syncthreads();
    }
    int excl = sm[t] - run;
    bkStart[2 * t] = excl;
    bkStart[2 * t + 1] = excl + v0;
    if (t == 255) bkStart[NBK] = sm[255];
}

// Pass 2: scatter packed keys {self|dstLocalGraph(12)|src(17)} bucket-major.
__global__ void __launch_bounds__(256) k_part(
        const int* __restrict__ src, const int* __restrict__ dst,
        const int* __restrict__ bkBound, const int* __restrict__ localBase,
        const int* __restrict__ bkStart, uint* __restrict__ partsKey,
        int E, int M) {
    __shared__ int rk[NBK];
    __shared__ int runOff[NBK];
    __shared__ int base[NBK];
    __shared__ int bkB[NBK + 1];
    __shared__ uint sbuf[1024];
    __shared__ ushort sb2[1024];
    __shared__ int sms[256];
    int t = threadIdx.x, b = blockIdx.x;
    for (int k = t; k < NBK; k += 256) base[k] = bkStart[k] + localBase[b * NBK + k];
    for (int k = t; k <= NBK; k += 256) bkB[k] = bkBound[k];
    int per = (M + NPB - 1) / NPB;
    int lo = b * per;
    int hi = lo + per; if (hi > M) hi = M;
    for (int cb = lo; cb < hi; cb += 1024) {
        int cnt = hi - cb; if (cnt > 1024) cnt = 1024;
        for (int k = t; k < NBK; k += 256) rk[k] = 0;
        __syncthreads();
        uint key_[4]; int bk_[4], r_[4]; bool v_[4];
#pragma unroll
        for (int q = 0; q < 4; q++) {              // batched coalesced loads
            int item = cb + q * 256 + t;
            v_[q] = item < hi;
            key_[q] = 0; bk_[q] = 0; r_[q] = 0;
            if (v_[q]) {
                int s, d; uint selfBit;
                if (item < E) { s = src[item]; d = dst[item]; selfBit = 0u; }
                else          { s = item - E;  d = s; selfBit = 1u << 29; }
                int bk = bksearch(bkB, d);
                bk_[q] = bk;
                int dLG = d - bkB[(bk >> 3) << 3];     // graph-local node id
                key_[q] = selfBit | ((uint)dLG << 17) | (uint)s;
            }
        }
#pragma unroll
        for (int q = 0; q < 4; q++)
            if (v_[q]) r_[q] = atomicAdd(&rk[bk_[q]], 1);
        __syncthreads();
        {   // pair-scan rk[512] -> runOff (exclusive)
            int v0 = rk[2 * t], v1 = rk[2 * t + 1];
            int run = v0 + v1;
            sms[t] = run; __syncthreads();
            for (int off = 1; off < 256; off <<= 1) {
                int a = (t >= off) ? sms[t - off] : 0;
                __syncthreads();
                sms[t] += a; __syncthreads();
            }
            int excl = sms[t] - run;
            runOff[2 * t] = excl;
            runOff[2 * t + 1] = excl + v0;
        }
        __syncthreads();
#pragma unroll
        for (int q = 0; q < 4; q++)                // LDS sort by bucket
            if (v_[q]) {
                int p = runOff[bk_[q]] + r_[q];
                sbuf[p] = key_[q];
                sb2[p] = (ushort)bk_[q];
            }
        __syncthreads();
#pragma unroll
        for (int q = 0; q < 4; q++) {              // coalesced run write-out
            int p = q * 256 + t;
            if (p < cnt) {
                int bk = sb2[p];
                partsKey[base[bk] + (p - runOff[bk])] = sbuf[p];
            }
        }
        __syncthreads();
        for (int k = t; k < NBK; k += 256) base[k] += rk[k];
        __syncthreads();
    }
}

// Per-bucket: count bucket-local dst -> nd densely.
__global__ void __launch_bounds__(256) k_cnt2(
        const uint* __restrict__ partsKey, const int* __restrict__ bkBound,
        const int* __restrict__ bkStart, const int* __restrict__ ids,
        float2* __restrict__ nd) {
    __shared__ int cnt[256];
    int b = blockIdx.x, t = threadIdx.x;
    cnt[t] = 0;
    __syncthreads();
    int nodeLo = bkBound[b];
    int gOff = nodeLo - bkBound[(b >> 3) << 3];  // bucket offset within graph
    int lo = bkStart[b], hi = bkStart[b + 1];
    for (int idx = lo + t; idx < hi; idx += 256) {
        uint key = partsKey[idx];
        if (!(key >> 29)) {
            int dL = (int)((key >> 17) & 0xFFF) - gOff;
            atomicAdd(&cnt[dL], 1);
        }
    }
    __syncthreads();
    int nn = bkBound[b + 1] - nodeLo;
    if (t < nn) {
        int i = nodeLo + t;
        nd[i] = make_float2(rsqrtf((float)(cnt[t] + 1)),
                            __int_as_float(ids[i]));
    }
}

// t1 = emb @ W1  (17 x 128)
__global__ void k_t1(const float* __restrict__ emb, const float* __restrict__ W1,
                     float* __restrict__ t1) {
    int t = blockIdx.x, f = threadIdx.x;
    float acc = 0.f;
    for (int k = 0; k < DDIM; k++) acc += emb[t * DDIM + k] * W1[k * DDIM + f];
    t1[t * DDIM + f] = acc;
}

// Per-bucket conv1: LDS bins CL[node][type], dense x1, then z = dinv*x1
// stored FP8 e4m3 (2 feats/lane -> ushort), row = 128 B.
__global__ void __launch_bounds__(256) k_x1b(
        const uint* __restrict__ partsKey, const int* __restrict__ bkBound,
        const int* __restrict__ bkStart, const float2* __restrict__ nd,
        const float* __restrict__ t1, const float* __restrict__ b1,
        ushort* __restrict__ z) {
    __shared__ float t1s[17 * DDIM];    // 8.7 KB
    __shared__ float CL[256 * 17];      // 17.4 KB
    __shared__ float2 ndL[256];
    __shared__ float bL[DDIM];
    int b = blockIdx.x, t = threadIdx.x;
    int nodeLo = bkBound[b], nn = bkBound[b + 1] - nodeLo;
    int gOff = nodeLo - bkBound[(b >> 3) << 3];
    for (int k = t; k < 17 * DDIM; k += 256) t1s[k] = t1[k];
    for (int k = t; k < 256 * 17; k += 256) CL[k] = 0.f;
    if (t < DDIM) bL[t] = b1[t];
    if (t < nn) ndL[t] = nd[nodeLo + t];
    __syncthreads();
    int lo = bkStart[b], hi = bkStart[b + 1];
    for (int cb = lo; cb < hi; cb += 1024) {
        uint key_[4]; bool v_[4];
#pragma unroll
        for (int q = 0; q < 4; q++) {
            int idx = cb + q * 256 + t;
            v_[q] = idx < hi;
            key_[q] = v_[q] ? partsKey[idx] : 0u;
        }
#pragma unroll
        for (int q = 0; q < 4; q++) {
            if (v_[q]) {
                uint key = key_[q];
                if (!(key >> 29)) {                 // real edge -> conv1 bin
                    int s = key & 0x1FFFF;
                    int dL = (int)((key >> 17) & 0xFFF) - gOff;
                    float2 ns = nd[s];              // random 8B gather (batched)
                    atomicAdd(&CL[dL * 17 + __float_as_int(ns.y)], ns.x);
                }
            }
        }
    }
    __syncthreads();
    int lane = t & 63, wave = t >> 6;
    for (int n = wave; n < nn; n += 4) {
        float dinv = ndL[n].x;
        int ti = __float_as_int(ndL[n].y);
        float ax = dinv * t1s[ti * DDIM + lane];
        float ay = dinv * t1s[ti * DDIM + 64 + lane];
#pragma unroll
        for (int tt = 0; tt < 17; tt++) {
            float c = CL[n * 17 + tt];
            ax += c * t1s[tt * DDIM + lane];
            ay += c * t1s[tt * DDIM + 64 + lane];
        }
        float vx = bL[lane]      + dinv * ax;
        float vy = bL[64 + lane] + dinv * ay;
        vx = vx > 0.f ? vx : 0.f;
        vy = vy > 0.f ? vy : 0.f;
        // z = dinv * x1, fp8 e4m3 packed pair
        int pk = __builtin_amdgcn_cvt_pk_fp8_f32(dinv * vx, dinv * vy, 0, false);
        z[(size_t)(nodeLo + n) * 64 + lane] = (ushort)(pk & 0xFFFF);
    }
}

// conv2+pool: block owns one (graph, slice). Weight = dinv_d from LDS table
// (graph-local); rows are fp8 z (128 B). Register accumulation, 16-wide.
__global__ void __launch_bounds__(256) k_conv2g(
        const uint* __restrict__ partsKey, const int* __restrict__ bkStart,
        const int* __restrict__ gBound, const float2* __restrict__ nd,
        const ushort* __restrict__ z, float* __restrict__ poolY) {
    __shared__ float dinvG[MAXGN];      // 8 KB
    __shared__ uint  mk[4][64];
    __shared__ float red[4][DDIM];
    int t = threadIdx.x, lane = t & 63, wave = t >> 6;
    int b = blockIdx.x;
    int j = b >> 3;
    int g = (b & 7) * 8 + (j >> 5);
    int sl = j & 31;
    int nLo = gBound[g], nn = gBound[g + 1] - nLo;
    for (int k = t; k < nn; k += 256) dinvG[k] = nd[nLo + k].x;
    __syncthreads();
    int a = bkStart[g * BPG], bnd = bkStart[(g + 1) * BPG];
    long long len = bnd - a;
    int s0 = a + (int)(len * sl / SLICES);
    int s1 = a + (int)(len * (sl + 1) / SLICES);
    float ax = 0.f, ay = 0.f;
    for (int cb = s0 + wave * 64; cb < s1; cb += 4 * 64) {
        int idx = cb + lane;
        mk[wave][lane] = (idx < s1) ? partsKey[idx] : 0xFFFFFFFFu;
#pragma unroll
        for (int jj = 0; jj < 64; jj += 16) {
            uint kk[16]; uint vv[16];
#pragma unroll
            for (int k = 0; k < 16; k++) kk[k] = mk[wave][jj + k];
#pragma unroll
            for (int k = 0; k < 16; k++)
                vv[k] = (kk[k] != 0xFFFFFFFFu)
                      ? (uint)z[(size_t)(kk[k] & 0x1FFFF) * 64 + lane] : 0u;
#pragma unroll
            for (int k = 0; k < 16; k++) {
                if (kk[k] != 0xFFFFFFFFu) {
                    float w = dinvG[(kk[k] >> 17) & 0xFFF];  // LDS broadcast
                    v2f f = __builtin_amdgcn_cvt_pk_f32_fp8((int)vv[k], false);
                    ax += w * f.x;
                    ay += w * f.y;
                }
            }
        }
    }
    red[wave][lane] = ax;
    red[wave][64 + lane] = ay;
    __syncthreads();
    if (wave == 0) {
        float vx = red[0][lane] + red[1][lane] + red[2][lane] + red[3][lane];
        float vy = red[0][64 + lane] + red[1][64 + lane] + red[2][64 + lane] + red[3][64 + lane];
        atomicAdd(&poolY[g * DDIM + lane], vx);
        atomicAdd(&poolY[g * DDIM + 64 + lane], vy);
    }
}

// out[g] = b2 + (poolY[g]/cnt[g]) @ W2 ; cnt from gBound
__global__ void __launch_bounds__(128) k_out(
        const float* __restrict__ poolY, const int* __restrict__ gBound,
        const float* __restrict__ W2, const float* __restrict__ b2,
        float* __restrict__ out) {
    __shared__ float py[DDIM];
    int g = blockIdx.x, f = threadIdx.x;
    py[f] = poolY[g * DDIM + f];
    __syncthreads();
    float acc = 0.f;
    for (int k = 0; k < DDIM; k++) acc += py[k] * W2[k * DDIM + f];
    int c = gBound[g + 1] - gBound[g];
    out[g * DDIM + f] = (c > 0) ? (b2[f] + acc / (float)c) : 0.f;
}

extern "C" void kernel_launch(void* const* d_in, const int* in_sizes, int n_in,
                              void* d_out, int out_size, void* d_ws, size_t ws_size,
                              hipStream_t stream) {
    const int* node_ids = (const int*)d_in[0];
    const int* edge_index = (const int*)d_in[1];
    const int* batch = (const int*)d_in[2];
    const float* emb = (const float*)d_in[4];
    const float* W1 = (const float*)d_in[5];
    const float* b1 = (const float*)d_in[6];
    const float* W2 = (const float*)d_in[7];
    const float* b2 = (const float*)d_in[8];
    float* out = (float*)d_out;

    const int N = in_sizes[0];
    const int E = in_sizes[1] / 2;
    const int M = E + N;
    const int* src = edge_index;
    const int* dst = edge_index + E;

    char* ws = (char*)d_ws;
    size_t off = 0;
    auto carve = [&](size_t bytes) { char* p = ws + off; off = (off + bytes + 255) & ~size_t(255); return p; };
    ushort* z         = (ushort*)carve((size_t)N * 64 * 2);    // fp8x2, 128 B/row
    uint*   partsKey  = (uint*)carve((size_t)M * 4);           // self|dLG|src
    float2* nd        = (float2*)carve((size_t)N * 8);
    int*    blockHist = (int*)carve((size_t)NPB * NBK * 4);    // 4.2 MB
    int*    localBase = (int*)carve((size_t)NPB * NBK * 4);    // 4.2 MB
    int*    tot       = (int*)carve(NBK * 4);
    int*    bkStart   = (int*)carve((NBK + 1) * 4);
    int*    gBound    = (int*)carve((GMAX + 1) * 4);
    int*    bkBound   = (int*)carve((NBK + 1) * 4);
    float*  t1        = (float*)carve(17 * DDIM * 4);
    float*  poolY     = (float*)carve((size_t)GMAX * DDIM * 4);

    hipMemsetAsync(poolY, 0, (size_t)GMAX * DDIM * 4, stream);

    k_gb2<<<1, 256, 0, stream>>>(batch, N, gBound, bkBound);
    k_p1<<<NPB, 256, 0, stream>>>(dst, bkBound, blockHist, E, M);
    k_scanG<<<NBK, 256, 0, stream>>>(blockHist, localBase, tot);
    k_scanT<<<1, 256, 0, stream>>>(tot, bkStart);
    k_part<<<NPB, 256, 0, stream>>>(src, dst, bkBound, localBase, bkStart,
                                    partsKey, E, M);
    k_cnt2<<<NBK, 256, 0, stream>>>(partsKey, bkBound, bkStart, node_ids, nd);
    k_t1<<<17, DDIM, 0, stream>>>(emb, W1, t1);
    k_x1b<<<NBK, 256, 0, stream>>>(partsKey, bkBound, bkStart, nd, t1, b1, z);
    k_conv2g<<<GMAX * SLICES, 256, 0, stream>>>(partsKey, bkStart, gBound, nd, z, poolY);
    k_out<<<GMAX, 128, 0, stream>>>(poolY, gBound, W2, b2, out);
}

// Round 14
// 204.982 us; speedup vs baseline: 1.8969x; 1.0746x over previous
//
#include <hip/hip_runtime.h>
#include <hip/hip_bf16.h>

// GCN: x=emb[ids]; x1=relu(GCNConv(x,W1,b1)); y=Ahat@x1; out[g]=b2+(mean_g y)@W2
//
// Structure (R14): zero global scattered atomics; fp8 row gather.
//  - E edges partitioned into 512 dst-buckets (8 per graph, graph-aligned).
//    Key = {dstLocalGraph(12)|src(17)}.
//  - conv1 per-bucket in LDS (bins CL[node][type]), dense x1 compute.
//  - z[s] = dinv_s * x1[s] stored FP8 e4m3 (128 B/row): conv2 weight becomes
//    dinv_d only (LDS table per graph).
//  - R14: self-loops REMOVED from item space - x1b adds sum(dinv^2 * x1) per
//    bucket to poolY directly (fp32 path, 65k spread atomics). conv2g inner
//    loop branchless (sentinel dLG=2047, dinvG[2047]=0). x1b 8-wide gathers.
//  - conv2+pool: per-(graph,slice) register accumulation, 16-wide gathers.

#define DDIM 128
#define GMAX 64
#define BPG  8                 // buckets per graph
#define NBK  (GMAX * BPG)      // 512 buckets
#define NPB  2048              // partition blocks
#define SLICES 32              // conv2 blocks per graph
#define MAXGN 2048             // max nodes per graph (mean 1563, +12 sigma)
typedef unsigned int uint;
typedef unsigned short ushort;
typedef float v2f __attribute__((ext_vector_type(2)));

// gBound[65] (bsearch on sorted batch) and bkBound[513] (graph-aligned 8-way split)
__global__ void k_gb2(const int* __restrict__ batch, int N,
                      int* __restrict__ gBound, int* __restrict__ bkBound) {
    __shared__ int gB[GMAX + 1];
    int t = threadIdx.x;
    if (t <= GMAX) {
        int key = t, lo = 0, hi = N;
        while (lo < hi) {
            int mid = (lo + hi) >> 1;
            if (batch[mid] < key) lo = mid + 1; else hi = mid;
        }
        gB[t] = lo;
        gBound[t] = lo;
    }
    __syncthreads();
    for (int bk = t; bk <= NBK; bk += 256) {
        int v;
        if (bk == NBK) v = gB[GMAX];
        else {
            int g = bk >> 3, s = bk & 7;
            int A = gB[g], L = gB[g + 1] - A;
            v = A + (int)((long long)L * s / BPG);
        }
        bkBound[bk] = v;
    }
}

__device__ __forceinline__ int bksearch(const int* bkB, int idx) {
    int lo = 0, hi = NBK - 1;
#pragma unroll
    for (int it = 0; it < 9; it++) {           // 2^9 = 512
        int mid = (lo + hi + 1) >> 1;
        if (bkB[mid] <= idx) lo = mid; else hi = mid - 1;
    }
    return lo;
}

// Pass 1: per-block bucket histogram over E edges.
__global__ void __launch_bounds__(256) k_p1(
        const int* __restrict__ dst, const int* __restrict__ bkBound,
        int* __restrict__ blockHist, int E) {
    __shared__ int h[NBK];
    __shared__ int bkB[NBK + 1];
    int t = threadIdx.x;
    for (int k = t; k < NBK; k += 256) h[k] = 0;
    for (int k = t; k <= NBK; k += 256) bkB[k] = bkBound[k];
    __syncthreads();
    int per = (E + NPB - 1) / NPB;
    int lo = blockIdx.x * per;
    int hi = lo + per; if (hi > E) hi = E;
    for (int cb = lo; cb < hi; cb += 1024) {
        int idx_[4]; bool v_[4];
#pragma unroll
        for (int q = 0; q < 4; q++) {
            int item = cb + q * 256 + t;
            v_[q] = item < hi;
            idx_[q] = v_[q] ? dst[item] : 0;
        }
#pragma unroll
        for (int q = 0; q < 4; q++)
            if (v_[q]) atomicAdd(&h[bksearch(bkB, idx_[q])], 1);
    }
    __syncthreads();
    for (int k = t; k < NBK; k += 256) blockHist[blockIdx.x * NBK + k] = h[k];
}

// Per-bucket exclusive scan over NPB block histograms.
__global__ void __launch_bounds__(256) k_scanG(
        const int* __restrict__ blockHist, int* __restrict__ localBase,
        int* __restrict__ tot) {
    __shared__ int sm[256];
    int g = blockIdx.x, t = threadIdx.x;
    const int PER = NPB / 256;     // 8
    int v[PER], loc[PER];
    int run = 0;
#pragma unroll
    for (int q = 0; q < PER; q++) {
        v[q] = blockHist[(t * PER + q) * NBK + g];
        loc[q] = run;
        run += v[q];
    }
    sm[t] = run; __syncthreads();
    for (int off = 1; off < 256; off <<= 1) {
        int a = (t >= off) ? sm[t - off] : 0;
        __syncthreads();
        sm[t] += a; __syncthreads();
    }
    int excl = sm[t] - run;
#pragma unroll
    for (int q = 0; q < PER; q++)
        localBase[(t * PER + q) * NBK + g] = excl + loc[q];
    if (t == 255) tot[g] = sm[255];
}

// bkStart[513] from tot[512]
__global__ void __launch_bounds__(256) k_scanT(
        const int* __restrict__ tot, int* __restrict__ bkStart) {
    __shared__ int sm[256];
    int t = threadIdx.x;
    int v0 = tot[2 * t], v1 = tot[2 * t + 1];
    int run = v0 + v1;
    sm[t] = run; __syncthreads();
    for (int off = 1; off < 256; off <<= 1) {
        int a = (t >= off) ? sm[t - off] : 0;
        __syncthreads();
        sm[t] += a; __syncthreads();
    }
    int excl = sm[t] - run;
    bkStart[2 * t] = excl;
    bkStart[2 * t + 1] = excl + v0;
    if (t == 255) bkStart[NBK] = sm[255];
}

// Pass 2: scatter packed keys {dstLocalGraph(12)|src(17)} bucket-major.
__global__ void __launch_bounds__(256) k_part(
        const int* __restrict__ src, const int* __restrict__ dst,
        const int* __restrict__ bkBound, const int* __restrict__ localBase,
        const int* __restrict__ bkStart, uint* __restrict__ partsKey, int E) {
    __shared__ int rk[NBK];
    __shared__ int runOff[NBK];
    __shared__ int base[NBK];
    __shared__ int bkB[NBK + 1];
    __shared__ uint sbuf[1024];
    __shared__ ushort sb2[1024];
    __shared__ int sms[256];
    int t = threadIdx.x, b = blockIdx.x;
    for (int k = t; k < NBK; k += 256) base[k] = bkStart[k] + localBase[b * NBK + k];
    for (int k = t; k <= NBK; k += 256) bkB[k] = bkBound[k];
    int per = (E + NPB - 1) / NPB;
    int lo = b * per;
    int hi = lo + per; if (hi > E) hi = E;
    for (int cb = lo; cb < hi; cb += 1024) {
        int cnt = hi - cb; if (cnt > 1024) cnt = 1024;
        for (int k = t; k < NBK; k += 256) rk[k] = 0;
        __syncthreads();
        uint key_[4]; int bk_[4], r_[4]; bool v_[4];
#pragma unroll
        for (int q = 0; q < 4; q++) {              // batched coalesced loads
            int item = cb + q * 256 + t;
            v_[q] = item < hi;
            key_[q] = 0; bk_[q] = 0; r_[q] = 0;
            if (v_[q]) {
                int s = src[item], d = dst[item];
                int bk = bksearch(bkB, d);
                bk_[q] = bk;
                int dLG = d - bkB[(bk >> 3) << 3];     // graph-local node id
                key_[q] = ((uint)dLG << 17) | (uint)s;
            }
        }
#pragma unroll
        for (int q = 0; q < 4; q++)
            if (v_[q]) r_[q] = atomicAdd(&rk[bk_[q]], 1);
        __syncthreads();
        {   // pair-scan rk[512] -> runOff (exclusive)
            int v0 = rk[2 * t], v1 = rk[2 * t + 1];
            int run = v0 + v1;
            sms[t] = run; __syncthreads();
            for (int off = 1; off < 256; off <<= 1) {
                int a = (t >= off) ? sms[t - off] : 0;
                __syncthreads();
                sms[t] += a; __syncthreads();
            }
            int excl = sms[t] - run;
            runOff[2 * t] = excl;
            runOff[2 * t + 1] = excl + v0;
        }
        __syncthreads();
#pragma unroll
        for (int q = 0; q < 4; q++)                // LDS sort by bucket
            if (v_[q]) {
                int p = runOff[bk_[q]] + r_[q];
                sbuf[p] = key_[q];
                sb2[p] = (ushort)bk_[q];
            }
        __syncthreads();
#pragma unroll
        for (int q = 0; q < 4; q++) {              // coalesced run write-out
            int p = q * 256 + t;
            if (p < cnt) {
                int bk = sb2[p];
                partsKey[base[bk] + (p - runOff[bk])] = sbuf[p];
            }
        }
        __syncthreads();
        for (int k = t; k < NBK; k += 256) base[k] += rk[k];
        __syncthreads();
    }
}

// Per-bucket: count bucket-local dst -> nd densely.
__global__ void __launch_bounds__(256) k_cnt2(
        const uint* __restrict__ partsKey, const int* __restrict__ bkBound,
        const int* __restrict__ bkStart, const int* __restrict__ ids,
        float2* __restrict__ nd) {
    __shared__ int cnt[256];
    int b = blockIdx.x, t = threadIdx.x;
    cnt[t] = 0;
    __syncthreads();
    int nodeLo = bkBound[b];
    int gOff = nodeLo - bkBound[(b >> 3) << 3];  // bucket offset within graph
    int lo = bkStart[b], hi = bkStart[b + 1];
    for (int idx = lo + t; idx < hi; idx += 256) {
        uint key = partsKey[idx];
        int dL = (int)((key >> 17) & 0xFFF) - gOff;
        atomicAdd(&cnt[dL], 1);
    }
    __syncthreads();
    int nn = bkBound[b + 1] - nodeLo;
    if (t < nn) {
        int i = nodeLo + t;
        nd[i] = make_float2(rsqrtf((float)(cnt[t] + 1)),
                            __int_as_float(ids[i]));
    }
}

// t1 = emb @ W1  (17 x 128)
__global__ void k_t1(const float* __restrict__ emb, const float* __restrict__ W1,
                     float* __restrict__ t1) {
    int t = blockIdx.x, f = threadIdx.x;
    float acc = 0.f;
    for (int k = 0; k < DDIM; k++) acc += emb[t * DDIM + k] * W1[k * DDIM + f];
    t1[t * DDIM + f] = acc;
}

// Per-bucket conv1: LDS bins CL[node][type] (8-wide batched gathers), dense
// x1, z = dinv*x1 in FP8 e4m3; self-loop pool contribution (fp32) -> poolY.
__global__ void __launch_bounds__(256) k_x1b(
        const uint* __restrict__ partsKey, const int* __restrict__ bkBound,
        const int* __restrict__ bkStart, const float2* __restrict__ nd,
        const float* __restrict__ t1, const float* __restrict__ b1,
        ushort* __restrict__ z, float* __restrict__ poolY) {
    __shared__ float t1s[17 * DDIM];    // 8.7 KB
    __shared__ float CL[256 * 17];      // 17.4 KB
    __shared__ float2 ndL[256];
    __shared__ float bL[DDIM];
    __shared__ float redS[4][DDIM];     // self-pool reduce
    int b = blockIdx.x, t = threadIdx.x;
    int nodeLo = bkBound[b], nn = bkBound[b + 1] - nodeLo;
    int gOff = nodeLo - bkBound[(b >> 3) << 3];
    for (int k = t; k < 17 * DDIM; k += 256) t1s[k] = t1[k];
    for (int k = t; k < 256 * 17; k += 256) CL[k] = 0.f;
    if (t < DDIM) bL[t] = b1[t];
    if (t < nn) ndL[t] = nd[nodeLo + t];
    __syncthreads();
    int lo = bkStart[b], hi = bkStart[b + 1];
    for (int cb = lo; cb < hi; cb += 2048) {
        uint key_[8]; bool v_[8];
#pragma unroll
        for (int q = 0; q < 8; q++) {
            int idx = cb + q * 256 + t;
            v_[q] = idx < hi;
            key_[q] = v_[q] ? partsKey[idx] : 0u;
        }
#pragma unroll
        for (int q = 0; q < 8; q++) {
            if (v_[q]) {
                uint key = key_[q];
                int s = key & 0x1FFFF;
                int dL = (int)((key >> 17) & 0xFFF) - gOff;
                float2 ns = nd[s];              // random 8B gather (8 in flight)
                atomicAdd(&CL[dL * 17 + __float_as_int(ns.y)], ns.x);
            }
        }
    }
    __syncthreads();
    int lane = t & 63, wave = t >> 6;
    float sx = 0.f, sy = 0.f;                   // self-loop pool partials
    for (int n = wave; n < nn; n += 4) {
        float dinv = ndL[n].x;
        int ti = __float_as_int(ndL[n].y);
        float ax = dinv * t1s[ti * DDIM + lane];
        float ay = dinv * t1s[ti * DDIM + 64 + lane];
#pragma unroll
        for (int tt = 0; tt < 17; tt++) {
            float c = CL[n * 17 + tt];
            ax += c * t1s[tt * DDIM + lane];
            ay += c * t1s[tt * DDIM + 64 + lane];
        }
        float vx = bL[lane]      + dinv * ax;
        float vy = bL[64 + lane] + dinv * ay;
        vx = vx > 0.f ? vx : 0.f;
        vy = vy > 0.f ? vy : 0.f;
        // z = dinv * x1, fp8 e4m3 packed pair
        int pk = __builtin_amdgcn_cvt_pk_fp8_f32(dinv * vx, dinv * vy, 0, false);
        z[(size_t)(nodeLo + n) * 64 + lane] = (ushort)(pk & 0xFFFF);
        float d2 = dinv * dinv;
        sx += d2 * vx;                           // self loop, fp32 path
        sy += d2 * vy;
    }
    redS[wave][lane] = sx;
    redS[wave][64 + lane] = sy;
    __syncthreads();
    if (wave == 0) {
        int g = b >> 3;
        float vx = redS[0][lane] + redS[1][lane] + redS[2][lane] + redS[3][lane];
        float vy = redS[0][64 + lane] + redS[1][64 + lane]
                 + redS[2][64 + lane] + redS[3][64 + lane];
        atomicAdd(&poolY[g * DDIM + lane], vx);
        atomicAdd(&poolY[g * DDIM + 64 + lane], vy);
    }
}

// conv2+pool: block owns one (graph, slice). Weight = dinv_d from LDS table;
// rows fp8 z (128 B). Branchless: pad sentinel dLG=2047, dinvG[2047]=0.
__global__ void __launch_bounds__(256) k_conv2g(
        const uint* __restrict__ partsKey, const int* __restrict__ bkStart,
        const int* __restrict__ gBound, const float2* __restrict__ nd,
        const ushort* __restrict__ z, float* __restrict__ poolY) {
    __shared__ float dinvG[MAXGN];      // 8 KB
    __shared__ uint  mk[4][64];
    __shared__ float red[4][DDIM];
    int t = threadIdx.x, lane = t & 63, wave = t >> 6;
    int b = blockIdx.x;
    int j = b >> 3;
    int g = (b & 7) * 8 + (j >> 5);
    int sl = j & 31;
    int nLo = gBound[g], nn = gBound[g + 1] - nLo;
    for (int k = t; k < nn; k += 256) dinvG[k] = nd[nLo + k].x;
    if (t == 0) dinvG[MAXGN - 1] = 0.f;          // sentinel weight
    __syncthreads();
    int a = bkStart[g * BPG], bnd = bkStart[(g + 1) * BPG];
    long long len = bnd - a;
    int s0 = a + (int)(len * sl / SLICES);
    int s1 = a + (int)(len * (sl + 1) / SLICES);
    const uint SENT = (uint)(MAXGN - 1) << 17;   // dLG=2047, src=0
    float ax = 0.f, ay = 0.f;
    for (int cb = s0 + wave * 64; cb < s1; cb += 4 * 64) {
        int idx = cb + lane;
        mk[wave][lane] = (idx < s1) ? partsKey[idx] : SENT;
#pragma unroll
        for (int jj = 0; jj < 64; jj += 16) {
            uint kk[16]; uint vv[16];
#pragma unroll
            for (int k = 0; k < 16; k++) kk[k] = mk[wave][jj + k];
#pragma unroll
            for (int k = 0; k < 16; k++)
                vv[k] = (uint)z[(size_t)(kk[k] & 0x1FFFF) * 64 + lane];
#pragma unroll
            for (int k = 0; k < 16; k++) {
                float w = dinvG[(kk[k] >> 17) & 0xFFF];  // LDS broadcast
                v2f f = __builtin_amdgcn_cvt_pk_f32_fp8((int)vv[k], false);
                ax += w * f.x;
                ay += w * f.y;
            }
        }
    }
    red[wave][lane] = ax;
    red[wave][64 + lane] = ay;
    __syncthreads();
    if (wave == 0) {
        float vx = red[0][lane] + red[1][lane] + red[2][lane] + red[3][lane];
        float vy = red[0][64 + lane] + red[1][64 + lane] + red[2][64 + lane] + red[3][64 + lane];
        atomicAdd(&poolY[g * DDIM + lane], vx);
        atomicAdd(&poolY[g * DDIM + 64 + lane], vy);
    }
}

// out[g] = b2 + (poolY[g]/cnt[g]) @ W2 ; cnt from gBound
__global__ void __launch_bounds__(128) k_out(
        const float* __restrict__ poolY, const int* __restrict__ gBound,
        const float* __restrict__ W2, const float* __restrict__ b2,
        float* __restrict__ out) {
    __shared__ float py[DDIM];
    int g = blockIdx.x, f = threadIdx.x;
    py[f] = poolY[g * DDIM + f];
    __syncthreads();
    float acc = 0.f;
    for (int k = 0; k < DDIM; k++) acc += py[k] * W2[k * DDIM + f];
    int c = gBound[g + 1] - gBound[g];
    out[g * DDIM + f] = (c > 0) ? (b2[f] + acc / (float)c) : 0.f;
}

extern "C" void kernel_launch(void* const* d_in, const int* in_sizes, int n_in,
                              void* d_out, int out_size, void* d_ws, size_t ws_size,
                              hipStream_t stream) {
    const int* node_ids = (const int*)d_in[0];
    const int* edge_index = (const int*)d_in[1];
    const int* batch = (const int*)d_in[2];
    const float* emb = (const float*)d_in[4];
    const float* W1 = (const float*)d_in[5];
    const float* b1 = (const float*)d_in[6];
    const float* W2 = (const float*)d_in[7];
    const float* b2 = (const float*)d_in[8];
    float* out = (float*)d_out;

    const int N = in_sizes[0];
    const int E = in_sizes[1] / 2;
    const int* src = edge_index;
    const int* dst = edge_index + E;

    char* ws = (char*)d_ws;
    size_t off = 0;
    auto carve = [&](size_t bytes) { char* p = ws + off; off = (off + bytes + 255) & ~size_t(255); return p; };
    ushort* z         = (ushort*)carve((size_t)N * 64 * 2);    // fp8x2, 128 B/row
    uint*   partsKey  = (uint*)carve((size_t)E * 4);           // dLG|src
    float2* nd        = (float2*)carve((size_t)N * 8);
    int*    blockHist = (int*)carve((size_t)NPB * NBK * 4);    // 4.2 MB
    int*    localBase = (int*)carve((size_t)NPB * NBK * 4);    // 4.2 MB
    int*    tot       = (int*)carve(NBK * 4);
    int*    bkStart   = (int*)carve((NBK + 1) * 4);
    int*    gBound    = (int*)carve((GMAX + 1) * 4);
    int*    bkBound   = (int*)carve((NBK + 1) * 4);
    float*  t1        = (float*)carve(17 * DDIM * 4);
    float*  poolY     = (float*)carve((size_t)GMAX * DDIM * 4);

    hipMemsetAsync(poolY, 0, (size_t)GMAX * DDIM * 4, stream);

    k_gb2<<<1, 256, 0, stream>>>(batch, N, gBound, bkBound);
    k_p1<<<NPB, 256, 0, stream>>>(dst, bkBound, blockHist, E);
    k_scanG<<<NBK, 256, 0, stream>>>(blockHist, localBase, tot);
    k_scanT<<<1, 256, 0, stream>>>(tot, bkStart);
    k_part<<<NPB, 256, 0, stream>>>(src, dst, bkBound, localBase, bkStart,
                                    partsKey, E);
    k_cnt2<<<NBK, 256, 0, stream>>>(partsKey, bkBound, bkStart, node_ids, nd);
    k_t1<<<17, DDIM, 0, stream>>>(emb, W1, t1);
    k_x1b<<<NBK, 256, 0, stream>>>(partsKey, bkBound, bkStart, nd, t1, b1, z, poolY);
    k_conv2g<<<GMAX * SLICES, 256, 0, stream>>>(partsKey, bkStart, gBound, nd, z, poolY);
    k_out<<<GMAX, 128, 0, stream>>>(poolY, gBound, W2, b2, out);
}